// Round 8
// baseline (954.694 us; speedup 1.0000x reference)
//
#include <hip/hip_runtime.h>
#include <hip/hip_bf16.h>
#include <hip/hip_cooperative_groups.h>

// 2-layer GCN + CORAL head. 6 dispatches total.
//  1. preprocess (cooperative, 5 grid.syncs): zero deg -> compact int64->int32
//     -> dst-partitioned degree count (XCD-local atomics) -> scan -> fill
//  2. conv_w (W1+W2 -> transposed bf16 hi/lo)
//  3. gemm<true>  (fp32 x, split-bf16 MFMA, epilogue scales by dis, bf16 out)
//  4. agg<0>      (wave=node, 256B row gathers, unroll 16; relu+hi/lo out)
//  5. gemm<false> (h1 hi/lo planes)
//  6. agg<1>      (fused CORAL head)

#define FEAT 128
#define CHUNK 4096
typedef unsigned short u16;
typedef unsigned int u32;
typedef __attribute__((ext_vector_type(8))) short bf16x8;
typedef __attribute__((ext_vector_type(4))) float f32x4;
#define MFMA16 __builtin_amdgcn_mfma_f32_16x16x32_bf16

namespace cg = cooperative_groups;

__device__ inline u16 f2bf(float f) {
    __hip_bfloat16 b = __float2bfloat16(f);
    return __builtin_bit_cast(u16, b);
}
__device__ inline float bf2f(u16 u) {
    __hip_bfloat16 b = __builtin_bit_cast(__hip_bfloat16, u);
    return __bfloat162float(b);
}
__device__ inline float blo(u32 m) { return __uint_as_float(m << 16); }
__device__ inline float bhi(u32 m) { return __uint_as_float(m & 0xffff0000u); }

// ---------------- cooperative preprocess ----------------
__global__ __launch_bounds__(256, 4) void preprocess(
    const int* __restrict__ p, int* __restrict__ src32, int* __restrict__ dst32,
    int* __restrict__ deg, int* __restrict__ rowp, int* __restrict__ bsum,
    float* __restrict__ dis, int* __restrict__ ssrc, int E, int N, int nper,
    int nch) {
    cg::grid_group grid = cg::this_grid();
    __shared__ int sflag;
    __shared__ int tmp[256];
    const int tid = blockIdx.x * 256 + threadIdx.x;
    const int nthr = (int)gridDim.x * 256;

    // A: zero degree
    for (int i = tid; i < N; i += nthr) deg[i] = 0;

    // detect int64 vs int32 layout (block-uniform)
    if (threadIdx.x < 64) {
        int v = p[2 * (int)threadIdx.x + 1];
        unsigned long long b = __ballot(v != 0);
        if (threadIdx.x == 0) sflag = (b == 0ull) ? 1 : 0;
    }
    __syncthreads();
    const int m = sflag;
    grid.sync();

    // B: compact to int32 (pure streaming)
    for (int i = tid; i < E; i += nthr) {
        int s, d;
        if (m) { s = p[2 * (size_t)i]; d = p[2 * ((size_t)E + i)]; }
        else   { s = p[(size_t)i];     d = p[(size_t)E + i]; }
        src32[i] = s;
        dst32[i] = d;
    }
    grid.sync();

    // B2: dst-partitioned degree histogram (XCD-local atomics)
    {
        const int ntile = nch * 8;
        for (int t = blockIdx.x; t < ntile; t += gridDim.x) {
            const int part = t & 7;
            const int lo = part * nper, hi = lo + nper;
            const int i0 = (t >> 3) * CHUNK;
            const int iend = min(i0 + CHUNK, E);
            for (int i = i0 + threadIdx.x; i < iend; i += 256) {
                int d = dst32[i];
                if (d >= lo && d < hi) atomicAdd(&deg[d], 1);
            }
        }
    }
    grid.sync();

    // C: per-2048-block exclusive scan + fused deg_inv_sqrt
    {
        const int NB = (N + 2047) >> 11;
        if ((int)blockIdx.x < NB) {
            int idx = (int)blockIdx.x * 2048 + threadIdx.x * 8;
            int v[8]; int s = 0;
#pragma unroll
            for (int i = 0; i < 8; ++i) {
                int id = idx + i;
                v[i] = (id < N) ? deg[id] : 0;
                s += v[i];
                if (id < N) dis[id] = 1.0f / sqrtf((float)v[i] + 1.0f);
            }
            tmp[threadIdx.x] = s;
            __syncthreads();
            for (int off = 1; off < 256; off <<= 1) {
                int t = (threadIdx.x >= (unsigned)off) ? tmp[threadIdx.x - off] : 0;
                __syncthreads();
                tmp[threadIdx.x] += t;
                __syncthreads();
            }
            int excl = (threadIdx.x == 0) ? 0 : tmp[threadIdx.x - 1];
            if (threadIdx.x == 255) bsum[blockIdx.x] = tmp[255];
            int run = excl;
#pragma unroll
            for (int i = 0; i < 8; ++i) {
                int id = idx + i;
                if (id < N) rowp[id] = run;
                run += v[i];
            }
        }
    }
    grid.sync();

    // D: scan of block sums (block 0)
    if (blockIdx.x == 0) {
        const int NB = (N + 2047) >> 11;
        int v = ((int)threadIdx.x < NB) ? bsum[threadIdx.x] : 0;
        tmp[threadIdx.x] = v;
        __syncthreads();
        for (int off = 1; off < 256; off <<= 1) {
            int t = (threadIdx.x >= (unsigned)off) ? tmp[threadIdx.x - off] : 0;
            __syncthreads();
            tmp[threadIdx.x] += t;
            __syncthreads();
        }
        int excl = (threadIdx.x == 0) ? 0 : tmp[threadIdx.x - 1];
        if ((int)threadIdx.x < NB) bsum[threadIdx.x] = excl;
    }
    grid.sync();

    // E: dst-partitioned counting-sort fill. After this:
    //    beg(d) = bsum[d>>11] + rowp[d] - deg[d]
    {
        const int ntile = nch * 8;
        for (int t = blockIdx.x; t < ntile; t += gridDim.x) {
            const int part = t & 7;
            const int lo = part * nper, hi = lo + nper;
            const int i0 = (t >> 3) * CHUNK;
            const int iend = min(i0 + CHUNK, E);
            for (int i = i0 + threadIdx.x; i < iend; i += 256) {
                int d = dst32[i];
                if (d >= lo && d < hi) {
                    int pos = bsum[d >> 11] + atomicAdd(&rowp[d], 1);
                    ssrc[pos] = src32[i];
                }
            }
        }
    }
}

// ---- W1,W2 [k][col] fp32 -> transposed bf16 hi/lo planes [2][col][k] -------
__global__ void conv_w(const float* __restrict__ W1, const float* __restrict__ W2,
                       u16* __restrict__ th, u16* __restrict__ tl) {
    const int b = blockIdx.x;                  // 128 blocks
    const float* W = (b < 64) ? W1 : W2;
    const int base = (b < 64) ? 0 : 16384;
    int idx = (b & 63) * 256 + threadIdx.x;    // 16384 per matrix
    int k = idx >> 7, col = idx & 127;
    float v = W[idx];
    u16 h = f2bf(v);
    u16 l = f2bf(v - bf2f(h));
    th[base + col * 128 + k] = h;
    tl[base + col * 128 + k] = l;
}

// ---------------- MFMA GEMM: G[r][c] = bf16( dis[r] * sum_k X[r][k] W[k][c] )
// FP32IN: X fp32, hi/lo split in-register. Else X bf16 hi/lo row-major planes.
// W transposed bf16 hi/lo [col][128]. Block = 4 waves; wave owns 32 cols.
template <bool FP32IN>
__global__ __launch_bounds__(256) void gemm_mfma(
    const float* __restrict__ Xf,
    const u16* __restrict__ Xhi, const u16* __restrict__ Xlo,
    const u16* __restrict__ Whi, const u16* __restrict__ Wlo,
    const float* __restrict__ dis, u16* __restrict__ G, int n, int nt) {
    const int wave = threadIdx.x >> 6, lane = threadIdx.x & 63;
    const int l15 = lane & 15, hi4 = lane >> 4;

    bf16x8 bh[2][4], bl[2][4];
#pragma unroll
    for (int ct = 0; ct < 2; ++ct) {
        const int col = wave * 32 + ct * 16 + l15;
#pragma unroll
        for (int j = 0; j < 4; ++j) {
            const int off = col * 128 + j * 32 + hi4 * 8;
            bh[ct][j] = *(const bf16x8*)(Whi + off);
            bl[ct][j] = *(const bf16x8*)(Wlo + off);
        }
    }

    for (int rt = blockIdx.x; rt < nt; rt += gridDim.x) {
        const int r0 = rt * 16;
        const int row = min(r0 + l15, n - 1);
        bf16x8 ah[4], al[4];
        if (FP32IN) {
            const float* Xr = Xf + (size_t)row * FEAT;
#pragma unroll
            for (int j = 0; j < 4; ++j) {
                float4 v0 = *(const float4*)(Xr + j * 32 + hi4 * 8);
                float4 v1 = *(const float4*)(Xr + j * 32 + hi4 * 8 + 4);
                float vv[8] = {v0.x, v0.y, v0.z, v0.w, v1.x, v1.y, v1.z, v1.w};
                bf16x8 h8, l8;
#pragma unroll
                for (int e = 0; e < 8; ++e) {
                    u16 h = f2bf(vv[e]);
                    u16 l = f2bf(vv[e] - bf2f(h));
                    h8[e] = (short)h; l8[e] = (short)l;
                }
                ah[j] = h8; al[j] = l8;
            }
        } else {
#pragma unroll
            for (int j = 0; j < 4; ++j) {
                const size_t off = (size_t)row * FEAT + j * 32 + hi4 * 8;
                ah[j] = *(const bf16x8*)(Xhi + off);
                al[j] = *(const bf16x8*)(Xlo + off);
            }
        }
        float dr[4];
#pragma unroll
        for (int q = 0; q < 4; ++q) {
            const int r = r0 + hi4 * 4 + q;
            dr[q] = (r < n) ? dis[r] : 0.f;
        }
#pragma unroll
        for (int ct = 0; ct < 2; ++ct) {
            f32x4 a = {0.f, 0.f, 0.f, 0.f};
#pragma unroll
            for (int j = 0; j < 4; ++j) {
                a = MFMA16(ah[j], bh[ct][j], a, 0, 0, 0);
                a = MFMA16(al[j], bh[ct][j], a, 0, 0, 0);
                a = MFMA16(ah[j], bl[ct][j], a, 0, 0, 0);
                a = MFMA16(al[j], bl[ct][j], a, 0, 0, 0);
            }
            const int c0 = wave * 32 + ct * 16 + l15;
#pragma unroll
            for (int q = 0; q < 4; ++q) {
                const int r = r0 + hi4 * 4 + q;
                if (r < n) G[(size_t)r * FEAT + c0] = f2bf(a[q] * dr[q]);
            }
        }
    }
}

// ---------------- pull aggregate over row-major bf16 plane ----------------
// G rows pre-scaled by dis[row]; wave = node; lane covers 2 cols (u32);
// unroll 16 -> 16 row-gathers in flight.
// MODE 0: relu(dn*sum+b) -> bf16 hi/lo planes.  MODE 1: fused CORAL head.
template <int MODE>
__global__ __launch_bounds__(256) void agg_kernel(
    const u16* __restrict__ G, const int* __restrict__ rowp,
    const int* __restrict__ cnt, const int* __restrict__ bsum,
    const int* __restrict__ ssrc, const float* __restrict__ dis,
    const float* __restrict__ bias,
    u16* __restrict__ Ohi, u16* __restrict__ Olo,
    float* __restrict__ out, const float* __restrict__ wfc,
    const float* __restrict__ thb, int n) {
    const int wave = threadIdx.x >> 6, lane = threadIdx.x & 63;
    const int node = blockIdx.x * 4 + wave;
    if (node >= n) return;
    const u32* __restrict__ Gv = (const u32*)G;
    const int c = cnt[node];
    const int beg = bsum[node >> 11] + rowp[node] - c;
    const int end = beg + c;
    u32 uself = Gv[(size_t)node * 64 + lane];
    float ax = blo(uself), ay = bhi(uself);
    int j = beg;
    for (; j + 16 <= end; j += 16) {
        int s[16];
#pragma unroll
        for (int u = 0; u < 16; ++u) s[u] = ssrc[j + u];
        u32 m[16];
#pragma unroll
        for (int u = 0; u < 16; ++u) m[u] = Gv[(size_t)s[u] * 64 + lane];
#pragma unroll
        for (int u = 0; u < 16; ++u) { ax += blo(m[u]); ay += bhi(m[u]); }
    }
    for (; j + 4 <= end; j += 4) {
        int s[4];
#pragma unroll
        for (int u = 0; u < 4; ++u) s[u] = ssrc[j + u];
        u32 m[4];
#pragma unroll
        for (int u = 0; u < 4; ++u) m[u] = Gv[(size_t)s[u] * 64 + lane];
#pragma unroll
        for (int u = 0; u < 4; ++u) { ax += blo(m[u]); ay += bhi(m[u]); }
    }
    for (; j < end; ++j) {
        u32 m = Gv[(size_t)ssrc[j] * 64 + lane];
        ax += blo(m); ay += bhi(m);
    }
    const float dn = dis[node];
    const float2 bv = ((const float2*)bias)[lane];
    const float o0 = fmaxf(fmaf(dn, ax, bv.x), 0.f);
    const float o1 = fmaxf(fmaf(dn, ay, bv.y), 0.f);
    if (MODE == 0) {
        ushort2 h, l;
        h.x = f2bf(o0); l.x = f2bf(o0 - bf2f(h.x));
        h.y = f2bf(o1); l.y = f2bf(o1 - bf2f(h.y));
        ((ushort2*)Ohi)[(size_t)node * 64 + lane] = h;
        ((ushort2*)Olo)[(size_t)node * 64 + lane] = l;
    } else {
        const float2 wv = ((const float2*)wfc)[lane];
        float part = fmaf(o0, wv.x, o1 * wv.y);
#pragma unroll
        for (int m_ = 32; m_ >= 1; m_ >>= 1) part += __shfl_xor(part, m_, 64);
        if (lane < 4) out[(size_t)node * 4 + lane] = part + thb[lane];
    }
}

extern "C" void kernel_launch(void* const* d_in, const int* in_sizes, int n_in,
                              void* d_out, int out_size, void* d_ws, size_t ws_size,
                              hipStream_t stream) {
    const float* x   = (const float*)d_in[0];
    const int*   ei  = (const int*)d_in[1];
    const float* W1  = (const float*)d_in[2];
    const float* b1  = (const float*)d_in[3];
    const float* W2  = (const float*)d_in[4];
    const float* b2  = (const float*)d_in[5];
    const float* wfc = (const float*)d_in[6];
    const float* thb = (const float*)d_in[7];
    const int N = in_sizes[0] / FEAT;
    const int E = in_sizes[1] / 2;
    float* out = (float*)d_out;

    char* w = (char*)d_ws;
    int*   bsum  = (int*)w;                       // [<=256]
    int*   deg   = (int*)(w + 1024);              // [N]  (= cnt)
    int*   rowp  = deg + N;                       // [N]
    float* dis   = (float*)(rowp + N);            // [N]
    int*   src32 = (int*)(dis + N);               // [E]
    int*   dst32 = src32 + E;                     // [E]
    int*   ssrc  = dst32 + E;                     // [E]
    size_t off   = (((char*)(ssrc + E)) - w + 511) & ~(size_t)511;
    u16*   wh    = (u16*)(w + off);               // [2][128*128] hi (W1,W2)
    u16*   wl    = wh + 32768;                    // [2][128*128] lo
    u16*   g     = wl + 32768;                    // [N*128] bf16 row-major
    u16*   h1h   = g + (size_t)N * FEAT;          // [N*128]
    u16*   h1l   = h1h + (size_t)N * FEAT;        // [N*128]

    const int nper = (N + 7) / 8;
    const int nch  = (E + CHUNK - 1) / CHUNK;

    {
        int Ev = E, Nv = N, nperv = nper, nchv = nch;
        void* args[] = {(void*)&ei, (void*)&src32, (void*)&dst32, (void*)&deg,
                        (void*)&rowp, (void*)&bsum, (void*)&dis, (void*)&ssrc,
                        (void*)&Ev, (void*)&Nv, (void*)&nperv, (void*)&nchv};
        hipLaunchCooperativeKernel((void*)preprocess, dim3(1024), dim3(256),
                                   args, 0, stream);
    }

    conv_w<<<128, 256, 0, stream>>>(W1, W2, wh, wl);

    const int nt = (N + 15) / 16;
    const int gblocks = nt < 1024 ? nt : 1024;
    gemm_mfma<true><<<gblocks, 256, 0, stream>>>(x, nullptr, nullptr, wh, wl,
                                                 dis, g, N, nt);
    agg_kernel<0><<<(N + 3) / 4, 256, 0, stream>>>(g, rowp, deg, bsum, ssrc, dis, b1,
                                                   h1h, h1l, nullptr, nullptr, nullptr, N);
    gemm_mfma<false><<<gblocks, 256, 0, stream>>>(nullptr, h1h, h1l, wh + 16384,
                                                  wl + 16384, dis, g, N, nt);
    agg_kernel<1><<<(N + 3) / 4, 256, 0, stream>>>(g, rowp, deg, bsum, ssrc, dis, b2,
                                                   nullptr, nullptr, out, wfc, thb, N);
}

// Round 9
// 460.954 us; speedup vs baseline: 2.0711x; 2.0711x over previous
//
#include <hip/hip_runtime.h>
#include <hip/hip_bf16.h>

// 2-layer GCN + CORAL head. Champion structure (r6) + targeted wins.
//  - edge compaction int64->int32 + fused degree histogram (1 pass)
//  - scan1(+deg_inv_sqrt) -> scan2 -> dst-partitioned counting-sort fill
//  - split-bf16 MFMA GEMM, 3 products (ah*bh + al*bh + ah*bl); epilogue
//    scales row r by deg_inv_sqrt[r], stores ONE bf16 plane (256 B rows)
//  - pull aggregate: wave = node, 64 lanes x u32 (2 bf16 cols), unroll 16,
//    grid-stride; layer-1 fuses relu + bf16 hi/lo; layer-2 fuses CORAL head
//  - 10 dispatches, no cooperative sync (r8 lesson: grid.sync costs more
//    than a kernel boundary on 8-XCD CDNA4)

#define FEAT 128
#define CHUNK 4096
typedef unsigned short u16;
typedef unsigned int u32;
typedef __attribute__((ext_vector_type(8))) short bf16x8;
typedef __attribute__((ext_vector_type(4))) float f32x4;
#define MFMA16 __builtin_amdgcn_mfma_f32_16x16x32_bf16

__device__ inline u16 f2bf(float f) {
    __hip_bfloat16 b = __float2bfloat16(f);
    return __builtin_bit_cast(u16, b);
}
__device__ inline float bf2f(u16 u) {
    __hip_bfloat16 b = __builtin_bit_cast(__hip_bfloat16, u);
    return __bfloat162float(b);
}
__device__ inline float blo(u32 m) { return __uint_as_float(m << 16); }
__device__ inline float bhi(u32 m) { return __uint_as_float(m & 0xffff0000u); }

// ------------- compact edges to int32 + degree histogram (detect inlined) ----
__global__ __launch_bounds__(256) void compact_count(const int* __restrict__ p,
                                                     int* __restrict__ src32,
                                                     int* __restrict__ dst32,
                                                     int* __restrict__ cnt, int E) {
    __shared__ int sflag;
    if (threadIdx.x < 64) {
        int v = p[2 * (int)threadIdx.x + 1];
        unsigned long long b = __ballot(v != 0);
        if (threadIdx.x == 0) sflag = (b == 0ull) ? 1 : 0;
    }
    __syncthreads();
    const int m = sflag;
    int i = blockIdx.x * 256 + threadIdx.x;
    if (i >= E) return;
    int s, d;
    if (m) { s = p[2 * (size_t)i]; d = p[2 * ((size_t)E + i)]; }
    else   { s = p[(size_t)i];     d = p[(size_t)E + i]; }
    src32[i] = s;
    dst32[i] = d;
    atomicAdd(&cnt[d], 1);
}

// ---------------- scan1: block-exclusive scan + fused deg_inv_sqrt ----------
__global__ void scan1(const int* __restrict__ cnt, int* __restrict__ out,
                      int* __restrict__ bsum, float* __restrict__ dis, int n) {
    __shared__ int tmp[256];
    int base = blockIdx.x * 2048;
    int idx = base + threadIdx.x * 8;
    int v[8]; int s = 0;
#pragma unroll
    for (int i = 0; i < 8; ++i) {
        int id = idx + i;
        v[i] = (id < n) ? cnt[id] : 0;
        s += v[i];
        if (id < n) dis[id] = 1.0f / sqrtf((float)v[i] + 1.0f);
    }
    tmp[threadIdx.x] = s;
    __syncthreads();
    for (int off = 1; off < 256; off <<= 1) {
        int t = (threadIdx.x >= (unsigned)off) ? tmp[threadIdx.x - off] : 0;
        __syncthreads();
        tmp[threadIdx.x] += t;
        __syncthreads();
    }
    int excl = (threadIdx.x == 0) ? 0 : tmp[threadIdx.x - 1];
    if (threadIdx.x == 255) bsum[blockIdx.x] = tmp[255];
    int run = excl;
#pragma unroll
    for (int i = 0; i < 8; ++i) { int id = idx + i; if (id < n) out[id] = run; run += v[i]; }
}

__global__ void scan2(int* __restrict__ bsum, int nb) {
    __shared__ int tmp[256];
    int v = (threadIdx.x < (unsigned)nb) ? bsum[threadIdx.x] : 0;
    tmp[threadIdx.x] = v;
    __syncthreads();
    for (int off = 1; off < 256; off <<= 1) {
        int t = (threadIdx.x >= (unsigned)off) ? tmp[threadIdx.x - off] : 0;
        __syncthreads();
        tmp[threadIdx.x] += t;
        __syncthreads();
    }
    int excl = (threadIdx.x == 0) ? 0 : tmp[threadIdx.x - 1];
    if (threadIdx.x < (unsigned)nb) bsum[threadIdx.x] = excl;
}

// ---------------- counting-sort fill, dst-partitioned (8 XCD slices) ---------
// pos = bsum[d>>11] + fetch_add(rowp[d]). After this kernel:
//   beg(d) = bsum[d>>11] + rowp[d] - cnt[d]
__global__ __launch_bounds__(256) void fill_sorted(const int* __restrict__ src32,
                                                   const int* __restrict__ dst32,
                                                   int* __restrict__ rowp,
                                                   const int* __restrict__ bsum,
                                                   int* __restrict__ ssrc, int E,
                                                   int nper) {
    const int part = blockIdx.x & 7;
    const int lo = part * nper, hi = lo + nper;
    const int i0 = (int)(blockIdx.x >> 3) * CHUNK;
    const int iend = min(i0 + CHUNK, E);
    for (int i = i0 + threadIdx.x; i < iend; i += 256) {
        int d = dst32[i];
        if (d >= lo && d < hi) {
            int pos = bsum[d >> 11] + atomicAdd(&rowp[d], 1);
            ssrc[pos] = src32[i];
        }
    }
}

// ---- W1,W2 [k][col] fp32 -> transposed bf16 hi/lo planes [2][col][k] -------
__global__ void conv_w(const float* __restrict__ W1, const float* __restrict__ W2,
                       u16* __restrict__ th, u16* __restrict__ tl) {
    const int b = blockIdx.x;                  // 128 blocks
    const float* W = (b < 64) ? W1 : W2;
    const int base = (b < 64) ? 0 : 16384;
    int idx = (b & 63) * 256 + threadIdx.x;    // 16384 per matrix
    int k = idx >> 7, col = idx & 127;
    float v = W[idx];
    u16 h = f2bf(v);
    u16 l = f2bf(v - bf2f(h));
    th[base + col * 128 + k] = h;
    tl[base + col * 128 + k] = l;
}

// ---------------- MFMA GEMM: G[r][c] = bf16( dis[r] * sum_k X[r][k] W[k][c] )
// 3-product split: ah*bh + al*bh + ah*bl  (al*bl ~ 2^-18, dropped).
// FP32IN: X fp32, hi/lo split in-register. Else X bf16 hi/lo row-major planes.
template <bool FP32IN>
__global__ __launch_bounds__(256) void gemm_mfma(
    const float* __restrict__ Xf,
    const u16* __restrict__ Xhi, const u16* __restrict__ Xlo,
    const u16* __restrict__ Whi, const u16* __restrict__ Wlo,
    const float* __restrict__ dis, u16* __restrict__ G, int n, int nt) {
    const int wave = threadIdx.x >> 6, lane = threadIdx.x & 63;
    const int l15 = lane & 15, hi4 = lane >> 4;

    bf16x8 bh[2][4], bl[2][4];
#pragma unroll
    for (int ct = 0; ct < 2; ++ct) {
        const int col = wave * 32 + ct * 16 + l15;
#pragma unroll
        for (int j = 0; j < 4; ++j) {
            const int off = col * 128 + j * 32 + hi4 * 8;
            bh[ct][j] = *(const bf16x8*)(Whi + off);
            bl[ct][j] = *(const bf16x8*)(Wlo + off);
        }
    }

    for (int rt = blockIdx.x; rt < nt; rt += gridDim.x) {
        const int r0 = rt * 16;
        const int row = min(r0 + l15, n - 1);
        bf16x8 ah[4], al[4];
        if (FP32IN) {
            const float* Xr = Xf + (size_t)row * FEAT;
#pragma unroll
            for (int j = 0; j < 4; ++j) {
                float4 v0 = *(const float4*)(Xr + j * 32 + hi4 * 8);
                float4 v1 = *(const float4*)(Xr + j * 32 + hi4 * 8 + 4);
                float vv[8] = {v0.x, v0.y, v0.z, v0.w, v1.x, v1.y, v1.z, v1.w};
                bf16x8 h8, l8;
#pragma unroll
                for (int e = 0; e < 8; ++e) {
                    u16 h = f2bf(vv[e]);
                    u16 l = f2bf(vv[e] - bf2f(h));
                    h8[e] = (short)h; l8[e] = (short)l;
                }
                ah[j] = h8; al[j] = l8;
            }
        } else {
#pragma unroll
            for (int j = 0; j < 4; ++j) {
                const size_t off = (size_t)row * FEAT + j * 32 + hi4 * 8;
                ah[j] = *(const bf16x8*)(Xhi + off);
                al[j] = *(const bf16x8*)(Xlo + off);
            }
        }
        float dr[4];
#pragma unroll
        for (int q = 0; q < 4; ++q) {
            const int r = r0 + hi4 * 4 + q;
            dr[q] = (r < n) ? dis[r] : 0.f;
        }
#pragma unroll
        for (int ct = 0; ct < 2; ++ct) {
            f32x4 a = {0.f, 0.f, 0.f, 0.f};
#pragma unroll
            for (int j = 0; j < 4; ++j) {
                a = MFMA16(ah[j], bh[ct][j], a, 0, 0, 0);
                a = MFMA16(al[j], bh[ct][j], a, 0, 0, 0);
                a = MFMA16(ah[j], bl[ct][j], a, 0, 0, 0);
            }
            const int c0 = wave * 32 + ct * 16 + l15;
#pragma unroll
            for (int q = 0; q < 4; ++q) {
                const int r = r0 + hi4 * 4 + q;
                if (r < n) G[(size_t)r * FEAT + c0] = f2bf(a[q] * dr[q]);
            }
        }
    }
}

// ---------------- pull aggregate over row-major bf16 plane ----------------
// G rows pre-scaled by dis[row]; wave = node; lane covers 2 cols (u32);
// unroll 16 -> 16 row-gathers in flight; grid-stride over nodes.
// MODE 0: relu(dn*sum+b) -> bf16 hi/lo planes.  MODE 1: fused CORAL head.
template <int MODE>
__global__ __launch_bounds__(256) void agg_kernel(
    const u16* __restrict__ G, const int* __restrict__ rowp,
    const int* __restrict__ cnt, const int* __restrict__ bsum,
    const int* __restrict__ ssrc, const float* __restrict__ dis,
    const float* __restrict__ bias,
    u16* __restrict__ Ohi, u16* __restrict__ Olo,
    float* __restrict__ out, const float* __restrict__ wfc,
    const float* __restrict__ thb, int n) {
    const int wave = threadIdx.x >> 6, lane = threadIdx.x & 63;
    const int nstride = (int)gridDim.x * 4;
    const u32* __restrict__ Gv = (const u32*)G;
    for (int node = blockIdx.x * 4 + wave; node < n; node += nstride) {
        const int c = cnt[node];
        const int beg = bsum[node >> 11] + rowp[node] - c;
        const int end = beg + c;
        u32 uself = Gv[(size_t)node * 64 + lane];
        float ax = blo(uself), ay = bhi(uself);
        int j = beg;
        for (; j + 16 <= end; j += 16) {
            int s[16];
#pragma unroll
            for (int u = 0; u < 16; ++u) s[u] = ssrc[j + u];
            u32 m[16];
#pragma unroll
            for (int u = 0; u < 16; ++u) m[u] = Gv[(size_t)s[u] * 64 + lane];
#pragma unroll
            for (int u = 0; u < 16; ++u) { ax += blo(m[u]); ay += bhi(m[u]); }
        }
        for (; j + 4 <= end; j += 4) {
            int s[4];
#pragma unroll
            for (int u = 0; u < 4; ++u) s[u] = ssrc[j + u];
            u32 m[4];
#pragma unroll
            for (int u = 0; u < 4; ++u) m[u] = Gv[(size_t)s[u] * 64 + lane];
#pragma unroll
            for (int u = 0; u < 4; ++u) { ax += blo(m[u]); ay += bhi(m[u]); }
        }
        for (; j < end; ++j) {
            u32 m = Gv[(size_t)ssrc[j] * 64 + lane];
            ax += blo(m); ay += bhi(m);
        }
        const float dn = dis[node];
        const float2 bv = ((const float2*)bias)[lane];
        const float o0 = fmaxf(fmaf(dn, ax, bv.x), 0.f);
        const float o1 = fmaxf(fmaf(dn, ay, bv.y), 0.f);
        if (MODE == 0) {
            ushort2 h, l;
            h.x = f2bf(o0); l.x = f2bf(o0 - bf2f(h.x));
            h.y = f2bf(o1); l.y = f2bf(o1 - bf2f(h.y));
            ((ushort2*)Ohi)[(size_t)node * 64 + lane] = h;
            ((ushort2*)Olo)[(size_t)node * 64 + lane] = l;
        } else {
            const float2 wv = ((const float2*)wfc)[lane];
            float part = fmaf(o0, wv.x, o1 * wv.y);
#pragma unroll
            for (int m_ = 32; m_ >= 1; m_ >>= 1) part += __shfl_xor(part, m_, 64);
            if (lane < 4) out[(size_t)node * 4 + lane] = part + thb[lane];
        }
    }
}

extern "C" void kernel_launch(void* const* d_in, const int* in_sizes, int n_in,
                              void* d_out, int out_size, void* d_ws, size_t ws_size,
                              hipStream_t stream) {
    const float* x   = (const float*)d_in[0];
    const int*   ei  = (const int*)d_in[1];
    const float* W1  = (const float*)d_in[2];
    const float* b1  = (const float*)d_in[3];
    const float* W2  = (const float*)d_in[4];
    const float* b2  = (const float*)d_in[5];
    const float* wfc = (const float*)d_in[6];
    const float* thb = (const float*)d_in[7];
    const int N = in_sizes[0] / FEAT;
    const int E = in_sizes[1] / 2;
    float* out = (float*)d_out;

    char* w = (char*)d_ws;
    int*   bsum  = (int*)w;                       // [<=256]
    int*   deg   = (int*)(w + 1024);              // [N]  (= cnt)
    int*   rowp  = deg + N;                       // [N]
    float* dis   = (float*)(rowp + N);            // [N]
    int*   src32 = (int*)(dis + N);               // [E]
    int*   dst32 = src32 + E;                     // [E]
    int*   ssrc  = dst32 + E;                     // [E]
    size_t off   = (((char*)(ssrc + E)) - w + 511) & ~(size_t)511;
    u16*   wh    = (u16*)(w + off);               // [2][128*128] hi (W1,W2)
    u16*   wl    = wh + 32768;                    // [2][128*128] lo
    u16*   g     = wl + 32768;                    // [N*128] bf16 row-major
    u16*   h1h   = g + (size_t)N * FEAT;          // [N*128]
    u16*   h1l   = h1h + (size_t)N * FEAT;        // [N*128]

    const int nper = (N + 7) / 8;
    const int nch  = (E + CHUNK - 1) / CHUNK;
    const int NB   = (N + 2047) / 2048;

    hipMemsetAsync(deg, 0, (size_t)N * 4, stream);
    compact_count<<<(E + 255) / 256, 256, 0, stream>>>(ei, src32, dst32, deg, E);
    scan1<<<NB, 256, 0, stream>>>(deg, rowp, bsum, dis, N);
    scan2<<<1, 256, 0, stream>>>(bsum, NB);
    fill_sorted<<<nch * 8, 256, 0, stream>>>(src32, dst32, rowp, bsum, ssrc, E, nper);

    conv_w<<<128, 256, 0, stream>>>(W1, W2, wh, wl);

    const int nt = (N + 15) / 16;
    const int gblocks = nt < 1024 ? nt : 1024;
    gemm_mfma<true><<<gblocks, 256, 0, stream>>>(x, nullptr, nullptr, wh, wl,
                                                 dis, g, N, nt);
    agg_kernel<0><<<4096, 256, 0, stream>>>(g, rowp, deg, bsum, ssrc, dis, b1,
                                            h1h, h1l, nullptr, nullptr, nullptr, N);
    gemm_mfma<false><<<gblocks, 256, 0, stream>>>(nullptr, h1h, h1l, wh + 16384,
                                                  wl + 16384, dis, g, N, nt);
    agg_kernel<1><<<4096, 256, 0, stream>>>(g, rowp, deg, bsum, ssrc, dis, b2,
                                            nullptr, nullptr, out, wfc, thb, N);
}